// Round 6
// baseline (152.515 us; speedup 1.0000x reference)
//
#include <hip/hip_runtime.h>
#include <stdint.h>

// Problem constants
constexpr int C_IN  = 512;
constexpr int HW    = 784;            // 28*28
constexpr int NB    = 32;
constexpr int M_TOT = NB * HW;        // 25088
constexpr int N_TOT = 2000;
constexpr int NPAD  = 2048;
constexpr int IMG_STRIDE = C_IN * HW;
constexpr int OUT_BATCH  = N_TOT * HW;

// GEMM tiling: 128x128, BK=64, 8 K-tiles. A: LDS ring-3; B: direct-to-reg.
constexpr int TBM = 128;
constexpr int TBN = 128;
constexpr int NKT = C_IN / 64;        // 8

typedef __attribute__((ext_vector_type(8))) short bf16x8;
typedef __attribute__((ext_vector_type(4))) float f32x4;

__device__ __forceinline__ uint16_t f2bf(float f) {
    union { float f; uint32_t u; } x; x.f = f;
    return (uint16_t)((x.u + 0x8000u) >> 16);
}

__device__ __forceinline__ void gload_lds16(const void* g, void* l) {
    __builtin_amdgcn_global_load_lds(
        (const __attribute__((address_space(1))) void*)g,
        (__attribute__((address_space(3))) void*)l, 16, 0, 0);
}

// ---------------------------------------------------------------------------
// prep_a: Abf[m][k] = bf16(input) transposed through LDS; fused s2[m]
__global__ __launch_bounds__(256) void prep_a_kernel(const float* __restrict__ in,
                                                     short* __restrict__ Abf,
                                                     float* __restrict__ s2) {
    __shared__ __align__(16) char T[64 * 512 * 2];
    __shared__ float red[16][64];

    const int t = threadIdx.x;
    const int q = t & 15;
    const int part = t >> 4;
    const int m0q = blockIdx.x * 64 + q * 4;
    const uint32_t b  = (uint32_t)m0q / 784u;
    const uint32_t hw = (uint32_t)m0q % 784u;
    const float* base = in + (size_t)b * IMG_STRIDE + hw;

    float4 acc = make_float4(0.f, 0.f, 0.f, 0.f);
    const int c0 = part * 32;
#pragma unroll 4
    for (int c = c0; c < c0 + 32; ++c) {
        float4 v = *(const float4*)(base + (size_t)c * HW);
        acc.x = fmaf(v.x, v.x, acc.x);
        acc.y = fmaf(v.y, v.y, acc.y);
        acc.z = fmaf(v.z, v.z, acc.z);
        acc.w = fmaf(v.w, v.w, acc.w);
        uint16_t vals[4] = { f2bf(v.x), f2bf(v.y), f2bf(v.z), f2bf(v.w) };
        const uint32_t by0 = (uint32_t)(q * 4) * 1024u + (uint32_t)c * 2u;
#pragma unroll
        for (int j = 0; j < 4; ++j) {
            uint32_t bb = by0 + (uint32_t)j * 1024u;
            bb ^= ((bb >> 12) & 7u) << 4;
            *(uint16_t*)(T + bb) = vals[j];
        }
    }
    red[part][q * 4 + 0] = acc.x;
    red[part][q * 4 + 1] = acc.y;
    red[part][q * 4 + 2] = acc.z;
    red[part][q * 4 + 3] = acc.w;
    __syncthreads();
    if (t < 64) {
        float s = 0.f;
#pragma unroll
        for (int p = 0; p < 16; ++p) s += red[p][t];
        s2[blockIdx.x * 64 + t] = s;
    }
    short* dst = Abf + (size_t)blockIdx.x * 64 * 512;
#pragma unroll
    for (int i = 0; i < 16; ++i) {
        const int idx = i * 256 + t;
        const int row = idx >> 6, ch = idx & 63;
        uint32_t bb = (uint32_t)row * 1024u + (uint32_t)ch * 16u;
        bb ^= ((bb >> 12) & 7u) << 4;
        bf16x8 v = *(bf16x8*)(T + bb);
        *(bf16x8*)(dst + (size_t)row * 512 + ch * 8) = v;
    }
}

// ---------------------------------------------------------------------------
// prep_w: Wbf[p][k] = bf16(w), rows >= N_TOT zeroed; fused w2[p]
__global__ __launch_bounds__(256) void prep_w_kernel(const float* __restrict__ w,
                                                     short* __restrict__ Wbf,
                                                     float* __restrict__ w2) {
    const int wv = threadIdx.x >> 6, lane = threadIdx.x & 63;
    const int p = blockIdx.x * 4 + wv;
    bf16x8 o = (bf16x8)0;
    float s = 0.f;
    if (p < N_TOT) {
        const float* base = w + (size_t)p * C_IN + lane * 8;
        float4 a = *(const float4*)base;
        float4 c = *(const float4*)(base + 4);
        s = a.x*a.x + a.y*a.y + a.z*a.z + a.w*a.w
          + c.x*c.x + c.y*c.y + c.z*c.z + c.w*c.w;
        o[0] = (short)f2bf(a.x); o[1] = (short)f2bf(a.y);
        o[2] = (short)f2bf(a.z); o[3] = (short)f2bf(a.w);
        o[4] = (short)f2bf(c.x); o[5] = (short)f2bf(c.y);
        o[6] = (short)f2bf(c.z); o[7] = (short)f2bf(c.w);
    }
    *(bf16x8*)(Wbf + (size_t)p * C_IN + lane * 8) = o;
#pragma unroll
    for (int off = 32; off; off >>= 1) s += __shfl_down(s, off);
    if (lane == 0) w2[p] = s;
}

// ---------------------------------------------------------------------------
// gemm6: 128x128 tile, BK=64, 8 K-tiles.
//   A: LDS ring-3 (3 x 16 KB), global_load_lds x16B, prefetch depth 2,
//      slot swizzle (storage slot s holds logical k-group s^(row&7)) -> 2-way reads.
//   B: NO LDS — direct global->VGPR (L2-resident, 2 MB), register
//      double-buffer 1 tile ahead, compile-time immediate offsets.
//   Uniform gate s_waitcnt vmcnt(4): drains exactly {A(kt), B(kt)},
//      leaves A(kt+1) in flight (issue order per iter: B(kt+1) THEN A(kt+2)).
//   One barrier per K-tile. Fused relu(s2 - 2*acc + w2) epilogue.
__global__ __launch_bounds__(256, 3) void gemm6_kernel(const short* __restrict__ Abf,
                                                       const short* __restrict__ Wbf,
                                                       const float* __restrict__ s2,
                                                       const float* __restrict__ w2,
                                                       float* __restrict__ out) {
    __shared__ __align__(16) char smem[49152];    // 3 x 16 KB A buffers

    const int t = threadIdx.x;
    const int wv = t >> 6, lane = t & 63;
    const int lr = lane & 15, lg = lane >> 4;

    const int bid = blockIdx.x;
    const int bn = bid & 15;               // fast: 16 blocks share one A panel
    const int bm = bid >> 4;

    const short* Ab = Abf + (size_t)bm * TBM * C_IN;

    // ---- A staging: instr j dest byte = j*4096 + wv*1024 + lane*16
    //      -> row = j*32 + wv*8 + (lane>>3), storage slot = lane&7
    //      source logical k-group g = (lane&7) ^ (row&7) = (lane&7)^((lane>>3)&7)
    const int arow = wv * 8 + (lane >> 3);
    const int ag   = (lane & 7) ^ ((lane >> 3) & 7);
    const short* AsrcL = Ab + (size_t)arow * C_IN + ag * 8;
    const int adst = wv * 1024;

    // ---- wave -> output subtile (64m x 64n)
    const int wm = (wv >> 1) * 64;         // {0,64}
    const int wn = (wv & 1) * 64;          // {0,64}

    // ---- A frag reads: row wm+m*16+lr, slot (kk*4+lg)^(lr&7); row&7 == lr&7
    const int ab0 = (wm + lr) * 128 + ((lg ^ (lr & 7)) * 16);   // kk=0
    const int ab1 = ab0 ^ 64;                                   // kk=1 (slot^4)

    // ---- B per-lane bases: col = bn*128 + wn + n*16 + lr, k-offset lg*8
    const short* Bq0 = Wbf + (size_t)(bn * TBN + wn + lr) * C_IN + lg * 8;
    const short* Bq1 = Bq0 + 16 * C_IN;
    const short* Bq2 = Bq0 + 32 * C_IN;
    const short* Bq3 = Bq0 + 48 * C_IN;

    bf16x8 b0[4][2], b1[4][2];
    f32x4 acc[4][4] = {};

#define LOADB(tt, arr)                                                         \
    do {                                                                       \
        arr[0][0] = *(const bf16x8*)(Bq0 + (tt) * 64);                         \
        arr[0][1] = *(const bf16x8*)(Bq0 + (tt) * 64 + 32);                    \
        arr[1][0] = *(const bf16x8*)(Bq1 + (tt) * 64);                         \
        arr[1][1] = *(const bf16x8*)(Bq1 + (tt) * 64 + 32);                    \
        arr[2][0] = *(const bf16x8*)(Bq2 + (tt) * 64);                         \
        arr[2][1] = *(const bf16x8*)(Bq2 + (tt) * 64 + 32);                    \
    } while (0);                                                               \
    do {                                                                       \
        arr[3][0] = *(const bf16x8*)(Bq3 + (tt) * 64);                         \
        arr[3][1] = *(const bf16x8*)(Bq3 + (tt) * 64 + 32);                    \
    } while (0)

#define STAGEA(tt)                                                             \
    do {                                                                       \
        char* buf_ = smem + ((tt) % 3) * 16384;                                \
        const short* s_ = AsrcL + (tt) * 64;                                   \
        gload_lds16(s_,            buf_ + adst);                               \
        gload_lds16(s_ + 32 * 512, buf_ + adst + 4096);                        \
        gload_lds16(s_ + 64 * 512, buf_ + adst + 8192);                        \
        gload_lds16(s_ + 96 * 512, buf_ + adst + 12288);                       \
    } while (0)

#define COMPUTE(bb)                                                            \
    do {                                                                       \
        bf16x8 af[4];                                                          \
        _Pragma("unroll") for (int m = 0; m < 4; ++m)                          \
            af[m] = *(const bf16x8*)(buf + ab0 + m * 2048);                    \
        __builtin_amdgcn_s_setprio(1);                                         \
        _Pragma("unroll") for (int m = 0; m < 4; ++m)                          \
            _Pragma("unroll") for (int n = 0; n < 4; ++n)                      \
                acc[m][n] = __builtin_amdgcn_mfma_f32_16x16x32_bf16(           \
                    af[m], bb[n][0], acc[m][n], 0, 0, 0);                      \
        __builtin_amdgcn_s_setprio(0);                                         \
        _Pragma("unroll") for (int m = 0; m < 4; ++m)                          \
            af[m] = *(const bf16x8*)(buf + ab1 + m * 2048);                    \
        __builtin_amdgcn_s_setprio(1);                                         \
        _Pragma("unroll") for (int m = 0; m < 4; ++m)                          \
            _Pragma("unroll") for (int n = 0; n < 4; ++n)                      \
                acc[m][n] = __builtin_amdgcn_mfma_f32_16x16x32_bf16(           \
                    af[m], bb[n][1], acc[m][n], 0, 0, 0);                      \
        __builtin_amdgcn_s_setprio(0);                                         \
    } while (0)

    // prologue: B0, A0, A1  (gate_0 vmcnt(4) drains B0+A0, leaves A1)
    LOADB(0, b0);
    STAGEA(0);
    STAGEA(1);

#pragma unroll
    for (int kt = 0; kt < NKT; ++kt) {
        if (kt < NKT - 1) asm volatile("s_waitcnt vmcnt(4)" ::: "memory");
        else              asm volatile("s_waitcnt vmcnt(0)" ::: "memory");
        __builtin_amdgcn_sched_barrier(0);
        __builtin_amdgcn_s_barrier();      // A(kt) visible to all; buf (kt+2)%3 free
        __builtin_amdgcn_sched_barrier(0);

        if (kt + 1 < NKT) {                // B first (so gate leaves only A in flight)
            if (kt & 1) { LOADB(kt + 1, b0); }
            else        { LOADB(kt + 1, b1); }
        }
        if (kt + 2 < NKT) STAGEA(kt + 2);

        const char* buf = smem + (kt % 3) * 16384;
        if (kt & 1) { COMPUTE(b1); }
        else        { COMPUTE(b0); }
    }
#undef LOADB
#undef STAGEA
#undef COMPUTE

    // epilogue: relu(s2 - 2*acc + w2), float4 over 4 consecutive m (hw-contig)
#pragma unroll
    for (int m = 0; m < 4; ++m) {
        const int m_r = bm * TBM + wm + m * 16 + lg * 4;   // 4-aligned, 784%4==0
        const float4 s2v = *(const float4*)(s2 + m_r);
        const uint32_t ob  = (uint32_t)m_r / 784u;
        const uint32_t ohw = (uint32_t)m_r % 784u;
        float* obase = out + (size_t)ob * OUT_BATCH + ohw;
#pragma unroll
        for (int n = 0; n < 4; ++n) {
            const int n_o = bn * TBN + wn + n * 16 + lr;
            if (n_o < N_TOT) {
                const float wvv = w2[n_o];
                const f32x4 a = acc[m][n];
                float4 r;
                r.x = fmaxf(s2v.x - 2.f * a.x + wvv, 0.f);
                r.y = fmaxf(s2v.y - 2.f * a.y + wvv, 0.f);
                r.z = fmaxf(s2v.z - 2.f * a.z + wvv, 0.f);
                r.w = fmaxf(s2v.w - 2.f * a.w + wvv, 0.f);
                *(float4*)(obase + (size_t)n_o * HW) = r;
            }
        }
    }
}

// ---------------------------------------------------------------------------
extern "C" void kernel_launch(void* const* d_in, const int* in_sizes, int n_in,
                              void* d_out, int out_size, void* d_ws, size_t ws_size,
                              hipStream_t stream) {
    const float* in = (const float*)d_in[0];   // [32,512,28,28] fp32
    const float* w  = (const float*)d_in[1];   // [2000,512,1,1] fp32
    float* out = (float*)d_out;                // [32,2000,28,28] fp32

    const size_t offA  = 0;
    const size_t offW  = offA + (size_t)M_TOT * C_IN * sizeof(short);   // 25.7 MB
    const size_t offS2 = offW + (size_t)NPAD * C_IN * sizeof(short);    // +2.1 MB
    const size_t offW2 = offS2 + (size_t)M_TOT * sizeof(float);

    short* Abf = (short*)((char*)d_ws + offA);
    short* Wbf = (short*)((char*)d_ws + offW);
    float* s2  = (float*)((char*)d_ws + offS2);
    float* w2  = (float*)((char*)d_ws + offW2);

    prep_a_kernel<<<M_TOT / 64, 256, 0, stream>>>(in, Abf, s2);
    prep_w_kernel<<<NPAD / 4, 256, 0, stream>>>(w, Wbf, w2);

    // 196 m-tiles x 16 n-tiles, bn fast (A panel shared by consecutive blocks)
    gemm6_kernel<<<196 * 16, 256, 0, stream>>>(Abf, Wbf, s2, w2, out);
}